// Round 6
// baseline (438.609 us; speedup 1.0000x reference)
//
#include <hip/hip_runtime.h>

typedef unsigned short u16;
typedef unsigned int u32;
typedef short bf16x8 __attribute__((ext_vector_type(8)));
typedef float f32x4 __attribute__((ext_vector_type(4)));
typedef u16 u16x8 __attribute__((ext_vector_type(8)));
typedef u16 u16x4 __attribute__((ext_vector_type(4)));

typedef const __attribute__((address_space(1))) u32* gas_ptr;
typedef __attribute__((address_space(3))) u32* las_ptr;

#define LQ   4096
#define EMB  512
#define NB   4
#define MROWS (NB * LQ)            // 16384
#define QSCALE 0.04419417382415922f // 1/sqrt(512)

__device__ __forceinline__ u16 f2bf(float f) {
  unsigned u = __builtin_bit_cast(unsigned, f);
  u += 0x7fffu + ((u >> 16) & 1u);
  return (u16)(u >> 16);
}
__device__ __forceinline__ float bf2f(u16 h) {
  unsigned u = ((unsigned)h) << 16;
  return __builtin_bit_cast(float, u);
}

// ---------------- prep ----------------------------------------------------
__global__ void prep_w(const float* __restrict__ Wq, const float* __restrict__ bq,
                       const float* __restrict__ Wk, const float* __restrict__ bk,
                       const float* __restrict__ Wv, const float* __restrict__ bv,
                       u16* __restrict__ wqb, u16* __restrict__ wkb, u16* __restrict__ wvb,
                       float* __restrict__ bias) {
  int i = blockIdx.x * 256 + threadIdx.x;
  if (i < EMB * EMB) {
    wqb[i] = f2bf(Wq[i] * QSCALE);
    wkb[i] = f2bf(Wk[i]);
    wvb[i] = f2bf(Wv[i]);
  }
  if (i < EMB) {
    bias[i]           = bq[i] * QSCALE;
    bias[EMB + i]     = bk[i];
    bias[2 * EMB + i] = bv[i];
  }
}

__global__ void prep_x(const float* __restrict__ x, u16* __restrict__ xb) {
  int i = blockIdx.x * 256 + threadIdx.x;
  const float4* p = (const float4*)(x + (size_t)i * 8);
  float4 a = p[0], b = p[1];
  u16x8 o;
  o[0] = f2bf(a.x); o[1] = f2bf(a.y); o[2] = f2bf(a.z); o[3] = f2bf(a.w);
  o[4] = f2bf(b.x); o[5] = f2bf(b.y); o[6] = f2bf(b.z); o[7] = f2bf(b.w);
  *(u16x8*)(xb + (size_t)i * 8) = o;
}

// ---- stage one 128x64 bf16 tile (16KB) with 256 threads, gload_lds w=16 ---
__device__ __forceinline__ void stage128_256t(const u16* g, int ld, u16* lds, int tid) {
  int wave = tid >> 6;
#pragma unroll
  for (int p = 0; p < 4; ++p) {
    int c = tid + p * 256;           // chunk 0..1023
    int row = c >> 3, hh = c & 7;
    int h = hh ^ (row & 7);
    const u16* src = g + (size_t)row * ld + h * 8;
    u16* dst = lds + wave * 512 + p * 2048;
    __builtin_amdgcn_global_load_lds((gas_ptr)(const void*)src, (las_ptr)(void*)dst, 16, 0, 0);
  }
}

// ---- 128x128 GEMM core, dbuf + prefetch ----------------------------------
__device__ __forceinline__ void gemm_core_db(
    const u16* __restrict__ A, int lda,
    const u16* __restrict__ B, int ldb,
    int kIters, u16* lds,
    f32x4 acc[4][4], int tid, int lane, int wr, int wc)
{
  stage128_256t(A, lda, lds, tid);
  stage128_256t(B, ldb, lds + 8192, tid);
  for (int kb = 0; kb < kIters; ++kb) {
    u16* ldsA = lds + (kb & 1) * 16384;
    u16* ldsB = ldsA + 8192;
    __syncthreads();
    if (kb + 1 < kIters) {
      u16* nA = lds + ((kb + 1) & 1) * 16384;
      stage128_256t(A + (kb + 1) * 64, lda, nA, tid);
      stage128_256t(B + (kb + 1) * 64, ldb, nA + 8192, tid);
    }
#pragma unroll
    for (int s = 0; s < 2; ++s) {
      bf16x8 af[4], bfr[4];
#pragma unroll
      for (int m = 0; m < 4; ++m) {
        int row = wr * 64 + m * 16 + (lane & 15);
        int hh = (s * 4 + (lane >> 4)) ^ (row & 7);
        af[m] = *(const bf16x8*)(ldsA + row * 64 + hh * 8);
      }
#pragma unroll
      for (int n = 0; n < 4; ++n) {
        int row = wc * 64 + n * 16 + (lane & 15);
        int hh = (s * 4 + (lane >> 4)) ^ (row & 7);
        bfr[n] = *(const bf16x8*)(ldsB + row * 64 + hh * 8);
      }
#pragma unroll
      for (int m = 0; m < 4; ++m)
#pragma unroll
        for (int n = 0; n < 4; ++n)
          acc[m][n] = __builtin_amdgcn_mfma_f32_16x16x32_bf16(af[m], bfr[n], acc[m][n], 0, 0, 0);
    }
  }
}

// ---------------- K1: fused QKV projection GEMM --------------------------
__global__ __launch_bounds__(256, 2) void k_qkv(
    const u16* __restrict__ xb,
    const u16* __restrict__ w0, const u16* __restrict__ w1, const u16* __restrict__ w2,
    const float* __restrict__ bias,
    u16* __restrict__ o0, u16* __restrict__ o1, u16* __restrict__ o2)
{
  __shared__ __align__(16) u16 lds[32768];
  int bi = blockIdx.x;
  int which = bi >> 9;
  int t = bi & 511;
  int rt = t >> 2, ct = t & 3;
  const u16* W = (which == 0) ? w0 : (which == 1) ? w1 : w2;
  const float* bs = bias + which * EMB;
  int tid = threadIdx.x, lane = tid & 63, wave = tid >> 6;
  int wr = wave >> 1, wc = wave & 1;
  f32x4 acc[4][4];
#pragma unroll
  for (int m = 0; m < 4; ++m)
#pragma unroll
    for (int n = 0; n < 4; ++n) acc[m][n] = (f32x4)0.0f;

  gemm_core_db(xb + (size_t)rt * 128 * EMB, EMB,
               W + (size_t)ct * 128 * EMB, EMB, EMB / 64,
               lds, acc, tid, lane, wr, wc);

#pragma unroll
  for (int m = 0; m < 4; ++m)
#pragma unroll
    for (int n = 0; n < 4; ++n) {
      int row0 = rt * 128 + wr * 64 + m * 16 + ((lane >> 4) << 2);
      int col  = ct * 128 + wc * 64 + n * 16 + (lane & 15);
      float bv = bs[col];
      if (which < 2) {
        u16* out = (which == 0) ? o0 : o1;
#pragma unroll
        for (int r = 0; r < 4; ++r)
          out[(size_t)(row0 + r) * EMB + col] = f2bf(acc[m][n][r] + bv);
      } else {
        int b = row0 >> 12, l0 = row0 & (LQ - 1);
        u16x4 pk;
#pragma unroll
        for (int r = 0; r < 4; ++r) pk[r] = f2bf(acc[m][n][r] + bv);
        *(u16x4*)(o2 + ((size_t)(b * EMB + col)) * LQ + l0) = pk;
      }
    }
}

// ---------------- K2: S = Q K^T on causal (lower-tri) tiles --------------
__global__ __launch_bounds__(256, 2) void k_qk(
    const u16* __restrict__ Q, const u16* __restrict__ K,
    u16* __restrict__ S, int bstart)
{
  __shared__ __align__(16) u16 lds[32768];
  int t = blockIdx.x;
  int b_local = t / 528;
  int i = t - b_local * 528;
  int qi = (int)((sqrtf(8.f * (float)i + 1.f) - 1.f) * 0.5f);
  while ((qi + 1) * (qi + 2) / 2 <= i) ++qi;
  while (qi * (qi + 1) / 2 > i) --qi;
  int ki = i - qi * (qi + 1) / 2;
  int bg = bstart + b_local;

  int tid = threadIdx.x, lane = tid & 63, wave = tid >> 6;
  int wr = wave >> 1, wc = wave & 1;
  f32x4 acc[4][4];
#pragma unroll
  for (int m = 0; m < 4; ++m)
#pragma unroll
    for (int n = 0; n < 4; ++n) acc[m][n] = (f32x4)0.0f;

  gemm_core_db(Q + ((size_t)bg * LQ + qi * 128) * EMB, EMB,
               K + ((size_t)bg * LQ + ki * 128) * EMB, EMB, EMB / 64,
               lds, acc, tid, lane, wr, wc);

  u16* Sb = S + (size_t)b_local * LQ * LQ;
#pragma unroll
  for (int m = 0; m < 4; ++m)
#pragma unroll
    for (int n = 0; n < 4; ++n) {
      int row0 = qi * 128 + wr * 64 + m * 16 + ((lane >> 4) << 2);
      int col  = ki * 128 + wc * 64 + n * 16 + (lane & 15);
#pragma unroll
      for (int r = 0; r < 4; ++r) {
        int row = row0 + r;
        float v = (col > row) ? -1e9f : acc[m][n][r];
        Sb[(size_t)row * LQ + col] = f2bf(v);
      }
    }
}

// ---------------- K3: fused online-softmax + PV, M=128 / N=512 -----------
// 512 thr / 8 waves, wave layout 1M x 8N (each wave: 128 rows x its 64 cols).
// Softmax once per S element (thread owns rows r0,r0+64 x 8 keys, 8-lane
// shfl reduce); A (S-tile) loaded global->regs (coalesced, prefetch 1 ahead);
// P broadcast via 16KB LDS (swizzled A-frag layout); V dbuf 128KB via
// global_load_lds. Pipeline: softmax(i+1) VALU overlaps MFMA(i); P/sF/flag
// stores land in short write-phase after bar2. Rescale gated by flag
// (defer-max THR=8 -> rare). Grid: 32 rt x bc batches; 1 block/CU.
__global__ __launch_bounds__(512, 1) void k_pv3(
    const u16* __restrict__ S, const u16* __restrict__ Vt,
    float* __restrict__ out, int bstart, int bcount)
{
  __shared__ __align__(16) u16 sV[65536];    // 2 bufs x [512 cols][64 keys]
  __shared__ __align__(16) u16 sP[8192];     // [128][64] swizzled
  __shared__ float sF[128];
  __shared__ float sL[128];
  __shared__ int   sFlag[8];

  int bi = blockIdx.x;
  int rt = bi / bcount;
  int b_local = bi - rt * bcount;
  int bg = bstart + b_local;
  int total = 2 * (rt + 1);

  const u16* Sbase = S + ((size_t)b_local * LQ + rt * 128) * LQ;
  const u16* Vb = Vt + (size_t)bg * EMB * LQ;

  int tid = threadIdx.x, lane = tid & 63, wave = tid >> 6;
  int l15 = lane & 15, lhi = lane >> 4;
  int r0 = tid >> 3;             // softmax rows r0 and r0+64
  int cc = tid & 7;              // 8-key chunk within unit

  f32x4 acc[8][4];
#pragma unroll
  for (int m = 0; m < 8; ++m)
#pragma unroll
    for (int n = 0; n < 4; ++n) acc[m][n] = (f32x4)0.0f;
  float m0 = -3.0e38f, m1 = -3.0e38f, l0 = 0.f, l1 = 0.f;

  auto stageV = [&](int i, u16* buf) {
    const u16* gb = Vb + i * 64;
#pragma unroll
    for (int p = 0; p < 8; ++p) {
      int cb = wave * 512 + p * 64 + lane;
      int col = cb >> 3, h = (cb & 7) ^ (col & 7);
      __builtin_amdgcn_global_load_lds(
          (gas_ptr)(const void*)(gb + (size_t)col * LQ + h * 8),
          (las_ptr)(void*)(buf + wave * 4096 + p * 512), 16, 0, 0);
    }
  };
  auto issueA = [&](int i, u16x8 (&ar)[2]) {
    const u16* ga = Sbase + i * 64 + cc * 8;
    ar[0] = *(const u16x8*)(ga + (size_t)r0 * LQ);
    ar[1] = *(const u16x8*)(ga + (size_t)(r0 + 64) * LQ);
  };
  auto softmax = [&](u16x8 (&ar)[2], u16x8& pf0, u16x8& pf1, float& fo0, float& fo1) {
    float s0[8], s1[8];
#pragma unroll
    for (int j = 0; j < 8; ++j) { s0[j] = bf2f(ar[0][j]); s1[j] = bf2f(ar[1][j]); }
    float mx0 = fmaxf(fmaxf(fmaxf(s0[0], s0[1]), fmaxf(s0[2], s0[3])),
                      fmaxf(fmaxf(s0[4], s0[5]), fmaxf(s0[6], s0[7])));
    float mx1 = fmaxf(fmaxf(fmaxf(s1[0], s1[1]), fmaxf(s1[2], s1[3])),
                      fmaxf(fmaxf(s1[4], s1[5]), fmaxf(s1[6], s1[7])));
#pragma unroll
    for (int off = 1; off <= 4; off <<= 1) {
      mx0 = fmaxf(mx0, __shfl_xor(mx0, off));
      mx1 = fmaxf(mx1, __shfl_xor(mx1, off));
    }
    float mn0 = (mx0 > m0 + 8.f) ? mx0 : m0;
    float mn1 = (mx1 > m1 + 8.f) ? mx1 : m1;
    float f0 = __expf(m0 - mn0);     // == 1 when max kept
    float f1 = __expf(m1 - mn1);
    m0 = mn0; m1 = mn1;
    float t0 = 0.f, t1 = 0.f;
#pragma unroll
    for (int j = 0; j < 8; ++j) {
      float e0 = __expf(s0[j] - m0);
      float e1 = __expf(s1[j] - m1);
      t0 += e0; t1 += e1;
      pf0[j] = f2bf(e0); pf1[j] = f2bf(e1);
    }
#pragma unroll
    for (int off = 1; off <= 4; off <<= 1) {
      t0 += __shfl_xor(t0, off);
      t1 += __shfl_xor(t1, off);
    }
    l0 = l0 * f0 + t0;
    l1 = l1 * f1 + t1;
    fo0 = f0; fo1 = f1;
  };

  u16x8 ar0[2], ar1[2];
  // ---- prologue: unit 0 softmax before first barrier
  issueA(0, ar0);
  stageV(0, sV);
  issueA(1, ar1);                  // total >= 2 always
  {
    u16x8 pf0, pf1; float f0s, f1s;
    softmax(ar0, pf0, pf1, f0s, f1s);
    int hh = cc ^ (r0 & 7);
    *(u16x8*)(sP + r0 * 64 + hh * 8) = pf0;
    *(u16x8*)(sP + (r0 + 64) * 64 + hh * 8) = pf1;
    if (cc == 0) { sF[r0] = f0s; sF[r0 + 64] = f1s; }
    int fl = __any((f0s < 1.f) || (f1s < 1.f)) ? 1 : 0;
    if (lane == 0) sFlag[wave] = fl;
  }

  auto body = [&](int i, u16x8 (&cur)[2], u16x8 (&nxt)[2], u16* vb, u16* vbN) {
    __syncthreads();               // bar1: P(i), V(i), sF, flag ready
    bool have = (i + 1 < total);
    if (have) stageV(i + 1, vbN);
    if (i + 2 < total) issueA(i + 2, cur);
    int4 fA = *(const int4*)&sFlag[0];
    int4 fB = *(const int4*)&sFlag[4];
    if (fA.x | fA.y | fA.z | fA.w | fB.x | fB.y | fB.z | fB.w) {
#pragma unroll
      for (int m = 0; m < 8; ++m) {
        f32x4 sf = *(const f32x4*)&sF[m * 16 + lhi * 4];
#pragma unroll
        for (int n = 0; n < 4; ++n)
#pragma unroll
          for (int r = 0; r < 4; ++r) acc[m][n][r] *= sf[r];
      }
    }
    u16x8 pf0, pf1; float f0s = 1.f, f1s = 1.f;
    if (have) softmax(nxt, pf0, pf1, f0s, f1s);   // VALU overlaps MFMA below
    // ---- MFMA(i): P (shared) x V (per-wave 64 cols)
#pragma unroll
    for (int s = 0; s < 2; ++s) {
      bf16x8 bv[4];
#pragma unroll
      for (int n = 0; n < 4; ++n) {
        int col = wave * 64 + n * 16 + l15;
        bv[n] = *(const bf16x8*)(vb + col * 64 + ((s * 4 + lhi) ^ (col & 7)) * 8);
      }
#pragma unroll
      for (int m = 0; m < 8; ++m) {
        int row = m * 16 + l15;
        bf16x8 pa = *(const bf16x8*)(sP + row * 64 + ((s * 4 + lhi) ^ (row & 7)) * 8);
#pragma unroll
        for (int n = 0; n < 4; ++n)
          acc[m][n] = __builtin_amdgcn_mfma_f32_16x16x32_bf16(pa, bv[n], acc[m][n], 0, 0, 0);
      }
    }
    __syncthreads();               // bar2: all MFMA(i) done reading sP
    if (have) {
      int hh = cc ^ (r0 & 7);
      *(u16x8*)(sP + r0 * 64 + hh * 8) = pf0;
      *(u16x8*)(sP + (r0 + 64) * 64 + hh * 8) = pf1;
      if (cc == 0) { sF[r0] = f0s; sF[r0 + 64] = f1s; }
      int fl = __any((f0s < 1.f) || (f1s < 1.f)) ? 1 : 0;
      if (lane == 0) sFlag[wave] = fl;
    }
  };

  int half = total >> 1;
  for (int h = 0; h < half; ++h) {
    body(2 * h,     ar0, ar1, sV,         sV + 32768);
    body(2 * h + 1, ar1, ar0, sV + 32768, sV);
  }

  // ---- epilogue: normalize and store
  if (cc == 0) { sL[r0] = 1.0f / l0; sL[r0 + 64] = 1.0f / l1; }
  __syncthreads();
#pragma unroll
  for (int m = 0; m < 8; ++m) {
    f32x4 li = *(const f32x4*)&sL[m * 16 + lhi * 4];
#pragma unroll
    for (int r = 0; r < 4; ++r) {
      int grow = rt * 128 + m * 16 + lhi * 4 + r;
#pragma unroll
      for (int n = 0; n < 4; ++n) {
        int col = wave * 64 + n * 16 + l15;
        out[((size_t)bg * LQ + grow) * EMB + col] = acc[m][n][r] * li[r];
      }
    }
  }
}

// ---------------- host ----------------------------------------------------
extern "C" void kernel_launch(void* const* d_in, const int* in_sizes, int n_in,
                              void* d_out, int out_size, void* d_ws, size_t ws_size,
                              hipStream_t stream) {
  const float* x  = (const float*)d_in[0];
  const float* Wq = (const float*)d_in[1];
  const float* bq = (const float*)d_in[2];
  const float* Wk = (const float*)d_in[3];
  const float* bk = (const float*)d_in[4];
  const float* Wv = (const float*)d_in[5];
  const float* bv = (const float*)d_in[6];

  char* ws = (char*)d_ws;
  size_t off = 0;
  u16* xb  = (u16*)(ws + off); off += (size_t)MROWS * EMB * 2;
  u16* wqb = (u16*)(ws + off); off += (size_t)EMB * EMB * 2;
  u16* wkb = (u16*)(ws + off); off += (size_t)EMB * EMB * 2;
  u16* wvb = (u16*)(ws + off); off += (size_t)EMB * EMB * 2;
  float* bias = (float*)(ws + off); off += 3 * EMB * 4;
  off = (off + 255) & ~(size_t)255;
  u16* Qb  = (u16*)(ws + off); off += (size_t)MROWS * EMB * 2;
  u16* Kb  = (u16*)(ws + off); off += (size_t)MROWS * EMB * 2;
  u16* Vtb = (u16*)(ws + off); off += (size_t)MROWS * EMB * 2;
  size_t fixed = off;
  size_t s_full = (size_t)NB * LQ * LQ * 2;
  int bcap = (ws_size >= fixed + s_full) ? NB : 1;
  u16* Sb = (u16*)(ws + fixed);

  prep_w<<<(EMB * EMB + 255) / 256, 256, 0, stream>>>(Wq, bq, Wk, bk, Wv, bv,
                                                      wqb, wkb, wvb, bias);
  prep_x<<<(MROWS * EMB / 8) / 256, 256, 0, stream>>>(x, xb);

  k_qkv<<<1536, 256, 0, stream>>>(xb, wqb, wkb, wvb, bias, Qb, Kb, Vtb);

  for (int bs = 0; bs < NB; bs += bcap) {
    int bc = (bs + bcap <= NB) ? bcap : (NB - bs);
    k_qk<<<528 * bc, 256, 0, stream>>>(Qb, Kb, Sb, bs);
    k_pv3<<<32 * bc, 512, 0, stream>>>(Sb, Vtb, (float*)d_out, bs, bc);
  }
}

// Round 7
// 276.835 us; speedup vs baseline: 1.5844x; 1.5844x over previous
//
#include <hip/hip_runtime.h>

typedef unsigned short u16;
typedef unsigned int u32;
typedef short bf16x8 __attribute__((ext_vector_type(8)));
typedef float f32x4 __attribute__((ext_vector_type(4)));
typedef u16 u16x8 __attribute__((ext_vector_type(8)));
typedef u16 u16x4 __attribute__((ext_vector_type(4)));

typedef const __attribute__((address_space(1))) u32* gas_ptr;
typedef __attribute__((address_space(3))) u32* las_ptr;

#define LQ   4096
#define EMB  512
#define NB   4
#define MROWS (NB * LQ)            // 16384
#define QSCALE 0.04419417382415922f // 1/sqrt(512)

__device__ __forceinline__ u16 f2bf(float f) {
  unsigned u = __builtin_bit_cast(unsigned, f);
  u += 0x7fffu + ((u >> 16) & 1u);
  return (u16)(u >> 16);
}
__device__ __forceinline__ float bf2f(u16 h) {
  unsigned u = ((unsigned)h) << 16;
  return __builtin_bit_cast(float, u);
}

// ---------------- prep ----------------------------------------------------
__global__ void prep_w(const float* __restrict__ Wq, const float* __restrict__ bq,
                       const float* __restrict__ Wk, const float* __restrict__ bk,
                       const float* __restrict__ Wv, const float* __restrict__ bv,
                       u16* __restrict__ wqb, u16* __restrict__ wkb, u16* __restrict__ wvb,
                       float* __restrict__ bias) {
  int i = blockIdx.x * 256 + threadIdx.x;
  if (i < EMB * EMB) {
    wqb[i] = f2bf(Wq[i] * QSCALE);
    wkb[i] = f2bf(Wk[i]);
    wvb[i] = f2bf(Wv[i]);
  }
  if (i < EMB) {
    bias[i]           = bq[i] * QSCALE;
    bias[EMB + i]     = bk[i];
    bias[2 * EMB + i] = bv[i];
  }
}

__global__ void prep_x(const float* __restrict__ x, u16* __restrict__ xb) {
  int i = blockIdx.x * 256 + threadIdx.x;
  const float4* p = (const float4*)(x + (size_t)i * 8);
  float4 a = p[0], b = p[1];
  u16x8 o;
  o[0] = f2bf(a.x); o[1] = f2bf(a.y); o[2] = f2bf(a.z); o[3] = f2bf(a.w);
  o[4] = f2bf(b.x); o[5] = f2bf(b.y); o[6] = f2bf(b.z); o[7] = f2bf(b.w);
  *(u16x8*)(xb + (size_t)i * 8) = o;
}

// ---- stage one 128x64 bf16 tile (16KB) with 256 threads, gload_lds w=16 ---
__device__ __forceinline__ void stage128_256t(const u16* g, int ld, u16* lds, int tid) {
  int wave = tid >> 6;
#pragma unroll
  for (int p = 0; p < 4; ++p) {
    int c = tid + p * 256;           // chunk 0..1023
    int row = c >> 3, hh = c & 7;
    int h = hh ^ (row & 7);
    const u16* src = g + (size_t)row * ld + h * 8;
    u16* dst = lds + wave * 512 + p * 2048;
    __builtin_amdgcn_global_load_lds((gas_ptr)(const void*)src, (las_ptr)(void*)dst, 16, 0, 0);
  }
}

// ---- 128x128 GEMM core, dbuf + prefetch ----------------------------------
__device__ __forceinline__ void gemm_core_db(
    const u16* __restrict__ A, int lda,
    const u16* __restrict__ B, int ldb,
    int kIters, u16* lds,
    f32x4 acc[4][4], int tid, int lane, int wr, int wc)
{
  stage128_256t(A, lda, lds, tid);
  stage128_256t(B, ldb, lds + 8192, tid);
  for (int kb = 0; kb < kIters; ++kb) {
    u16* ldsA = lds + (kb & 1) * 16384;
    u16* ldsB = ldsA + 8192;
    __syncthreads();
    if (kb + 1 < kIters) {
      u16* nA = lds + ((kb + 1) & 1) * 16384;
      stage128_256t(A + (kb + 1) * 64, lda, nA, tid);
      stage128_256t(B + (kb + 1) * 64, ldb, nA + 8192, tid);
    }
#pragma unroll
    for (int s = 0; s < 2; ++s) {
      bf16x8 af[4], bfr[4];
#pragma unroll
      for (int m = 0; m < 4; ++m) {
        int row = wr * 64 + m * 16 + (lane & 15);
        int hh = (s * 4 + (lane >> 4)) ^ (row & 7);
        af[m] = *(const bf16x8*)(ldsA + row * 64 + hh * 8);
      }
#pragma unroll
      for (int n = 0; n < 4; ++n) {
        int row = wc * 64 + n * 16 + (lane & 15);
        int hh = (s * 4 + (lane >> 4)) ^ (row & 7);
        bfr[n] = *(const bf16x8*)(ldsB + row * 64 + hh * 8);
      }
#pragma unroll
      for (int m = 0; m < 4; ++m)
#pragma unroll
        for (int n = 0; n < 4; ++n)
          acc[m][n] = __builtin_amdgcn_mfma_f32_16x16x32_bf16(af[m], bfr[n], acc[m][n], 0, 0, 0);
    }
  }
}

// ---------------- K1: fused QKV projection GEMM --------------------------
__global__ __launch_bounds__(256, 2) void k_qkv(
    const u16* __restrict__ xb,
    const u16* __restrict__ w0, const u16* __restrict__ w1, const u16* __restrict__ w2,
    const float* __restrict__ bias,
    u16* __restrict__ o0, u16* __restrict__ o1, u16* __restrict__ o2)
{
  __shared__ __align__(16) u16 lds[32768];
  int bi = blockIdx.x;
  int which = bi >> 9;
  int t = bi & 511;
  int rt = t >> 2, ct = t & 3;
  const u16* W = (which == 0) ? w0 : (which == 1) ? w1 : w2;
  const float* bs = bias + which * EMB;
  int tid = threadIdx.x, lane = tid & 63, wave = tid >> 6;
  int wr = wave >> 1, wc = wave & 1;
  f32x4 acc[4][4];
#pragma unroll
  for (int m = 0; m < 4; ++m)
#pragma unroll
    for (int n = 0; n < 4; ++n) acc[m][n] = (f32x4)0.0f;

  gemm_core_db(xb + (size_t)rt * 128 * EMB, EMB,
               W + (size_t)ct * 128 * EMB, EMB, EMB / 64,
               lds, acc, tid, lane, wr, wc);

#pragma unroll
  for (int m = 0; m < 4; ++m)
#pragma unroll
    for (int n = 0; n < 4; ++n) {
      int row0 = rt * 128 + wr * 64 + m * 16 + ((lane >> 4) << 2);
      int col  = ct * 128 + wc * 64 + n * 16 + (lane & 15);
      float bv = bs[col];
      if (which < 2) {
        u16* out = (which == 0) ? o0 : o1;
#pragma unroll
        for (int r = 0; r < 4; ++r)
          out[(size_t)(row0 + r) * EMB + col] = f2bf(acc[m][n][r] + bv);
      } else {
        int b = row0 >> 12, l0 = row0 & (LQ - 1);
        u16x4 pk;
#pragma unroll
        for (int r = 0; r < 4; ++r) pk[r] = f2bf(acc[m][n][r] + bv);
        *(u16x4*)(o2 + ((size_t)(b * EMB + col)) * LQ + l0) = pk;
      }
    }
}

// ---------------- K2: S = Q K^T on causal (lower-tri) tiles --------------
__global__ __launch_bounds__(256, 2) void k_qk(
    const u16* __restrict__ Q, const u16* __restrict__ K,
    u16* __restrict__ S, int bstart)
{
  __shared__ __align__(16) u16 lds[32768];
  int t = blockIdx.x;
  int b_local = t / 528;
  int i = t - b_local * 528;
  int qi = (int)((sqrtf(8.f * (float)i + 1.f) - 1.f) * 0.5f);
  while ((qi + 1) * (qi + 2) / 2 <= i) ++qi;
  while (qi * (qi + 1) / 2 > i) --qi;
  int ki = i - qi * (qi + 1) / 2;
  int bg = bstart + b_local;

  int tid = threadIdx.x, lane = tid & 63, wave = tid >> 6;
  int wr = wave >> 1, wc = wave & 1;
  f32x4 acc[4][4];
#pragma unroll
  for (int m = 0; m < 4; ++m)
#pragma unroll
    for (int n = 0; n < 4; ++n) acc[m][n] = (f32x4)0.0f;

  gemm_core_db(Q + ((size_t)bg * LQ + qi * 128) * EMB, EMB,
               K + ((size_t)bg * LQ + ki * 128) * EMB, EMB, EMB / 64,
               lds, acc, tid, lane, wr, wc);

  u16* Sb = S + (size_t)b_local * LQ * LQ;
#pragma unroll
  for (int m = 0; m < 4; ++m)
#pragma unroll
    for (int n = 0; n < 4; ++n) {
      int row0 = qi * 128 + wr * 64 + m * 16 + ((lane >> 4) << 2);
      int col  = ki * 128 + wc * 64 + n * 16 + (lane & 15);
#pragma unroll
      for (int r = 0; r < 4; ++r) {
        int row = row0 + r;
        float v = (col > row) ? -1e9f : acc[m][n][r];
        Sb[(size_t)row * LQ + col] = f2bf(v);
      }
    }
}

// ---------------- K3: fused online-softmax + PV, M=128 / N=512 -----------
// 1024 thr / 16 waves (2M x 8N): acc[4][4] = 64 VGPR/thread (fits the hard
// 128-VGPR cap of 16 waves/CU -> no spill). Softmax once per S element
// (thread owns 1 row x 8 keys, 8-lane shfl reduce). Pipeline per unit:
//   bar -> stageV(i+1) -> issueA(i+1) -> [rescale if flagged] -> MFMA(i)
//       -> softmax(i+1) (A latency hidden under MFMA) -> bar -> write P/sF/flag
// LDS: V dbuf 128KB + P 16KB + stats ~145KB. Grid 32rt x bc, 1 block/CU.
__global__ __launch_bounds__(1024) void k_pv3(
    const u16* __restrict__ S, const u16* __restrict__ Vt,
    float* __restrict__ out, int bstart, int bcount)
{
  __shared__ __align__(16) u16 sV[65536];    // 2 bufs x [512 cols][64 keys]
  __shared__ __align__(16) u16 sP[8192];     // [128][64] swizzled
  __shared__ float sF[128];
  __shared__ float sL[128];
  __shared__ int   sFlag[16];

  int bi = blockIdx.x;
  int rt = bi / bcount;
  int b_local = bi - rt * bcount;
  int bg = bstart + b_local;
  int units = 2 * (rt + 1);

  const u16* Sbase = S + ((size_t)b_local * LQ + rt * 128) * LQ;
  const u16* Vb = Vt + (size_t)bg * EMB * LQ;

  int tid = threadIdx.x, lane = tid & 63, wave = tid >> 6;
  int l15 = lane & 15, lhi = lane >> 4;
  int wr = wave >> 3, wn = wave & 7;   // 2M x 8N
  int r0 = tid >> 3;                   // softmax row 0..127
  int cc = tid & 7;                    // 8-key chunk

  f32x4 acc[4][4];
#pragma unroll
  for (int m = 0; m < 4; ++m)
#pragma unroll
    for (int n = 0; n < 4; ++n) acc[m][n] = (f32x4)0.0f;
  float mrun = -3.0e38f, lrun = 0.f;

  auto stageV = [&](int i, u16* buf) {
    const u16* gb = Vb + i * 64;
#pragma unroll
    for (int p = 0; p < 4; ++p) {
      int c = tid + p * 1024;          // chunk 0..4095
      int col = c >> 3, h = (c & 7) ^ (col & 7);
      __builtin_amdgcn_global_load_lds(
          (gas_ptr)(const void*)(gb + (size_t)col * LQ + h * 8),
          (las_ptr)(void*)(buf + wave * 512 + p * 8192), 16, 0, 0);
    }
  };

  auto softmax = [&](u16x8 ar, u16x8& pf, float& fo) {
    float sv[8];
#pragma unroll
    for (int j = 0; j < 8; ++j) sv[j] = bf2f(ar[j]);
    float mx = fmaxf(fmaxf(fmaxf(sv[0], sv[1]), fmaxf(sv[2], sv[3])),
                     fmaxf(fmaxf(sv[4], sv[5]), fmaxf(sv[6], sv[7])));
#pragma unroll
    for (int off = 1; off <= 4; off <<= 1) mx = fmaxf(mx, __shfl_xor(mx, off));
    float mn = (mx > mrun + 8.f) ? mx : mrun;   // defer-max THR=8
    float f = __expf(mrun - mn);                // ==1 when max kept
    mrun = mn;
    float t = 0.f;
#pragma unroll
    for (int j = 0; j < 8; ++j) {
      float e = __expf(sv[j] - mrun);
      t += e;
      pf[j] = f2bf(e);
    }
#pragma unroll
    for (int off = 1; off <= 4; off <<= 1) t += __shfl_xor(t, off);
    lrun = lrun * f + t;
    fo = f;
  };

  int hhP = (cc ^ (r0 & 7)) * 8;       // swizzled u16 offset for this thread's P

  // ---- prologue: V(0), A(0), softmax(0), publish P(0)/sF/flag
  stageV(0, sV);
  {
    u16x8 ar = *(const u16x8*)(Sbase + (size_t)r0 * LQ + cc * 8);
    u16x8 pf; float f;
    softmax(ar, pf, f);
    *(u16x8*)(sP + r0 * 64 + hhP) = pf;
    if (cc == 0) sF[r0] = f;
    int fl = __any(f < 1.f) ? 1 : 0;
    if (lane == 0) sFlag[wave] = fl;
  }

  for (int i = 0; i < units; ++i) {
    u16* vb = sV + (i & 1) * 32768;
    __syncthreads();                   // V(i) staged, P(i)/sF/flag visible
    bool have = (i + 1 < units);
    if (have) stageV(i + 1, sV + ((i + 1) & 1) * 32768);
    u16x8 ar;
    if (have) ar = *(const u16x8*)(Sbase + (i + 1) * 64 + (size_t)r0 * LQ + cc * 8);

    // rescale acc by per-row factor when any row updated its max
    int4 fA = *(const int4*)&sFlag[0];
    int4 fB = *(const int4*)&sFlag[4];
    int4 fC = *(const int4*)&sFlag[8];
    int4 fD = *(const int4*)&sFlag[12];
    if ((fA.x | fA.y | fA.z | fA.w) | (fB.x | fB.y | fB.z | fB.w) |
        (fC.x | fC.y | fC.z | fC.w) | (fD.x | fD.y | fD.z | fD.w)) {
#pragma unroll
      for (int m = 0; m < 4; ++m) {
        f32x4 sf = *(const f32x4*)&sF[wr * 64 + m * 16 + lhi * 4];
#pragma unroll
        for (int n = 0; n < 4; ++n)
#pragma unroll
          for (int r = 0; r < 4; ++r) acc[m][n][r] *= sf[r];
      }
    }

    // ---- MFMA(i): P (shared) x V (per-wave 64 cols)
#pragma unroll
    for (int s = 0; s < 2; ++s) {
      bf16x8 bv[4];
#pragma unroll
      for (int n = 0; n < 4; ++n) {
        int col = wn * 64 + n * 16 + l15;
        bv[n] = *(const bf16x8*)(vb + col * 64 + ((s * 4 + lhi) ^ (col & 7)) * 8);
      }
#pragma unroll
      for (int m = 0; m < 4; ++m) {
        int row = wr * 64 + m * 16 + l15;
        bf16x8 pa = *(const bf16x8*)(sP + row * 64 + ((s * 4 + lhi) ^ (row & 7)) * 8);
#pragma unroll
        for (int n = 0; n < 4; ++n)
          acc[m][n] = __builtin_amdgcn_mfma_f32_16x16x32_bf16(pa, bv[n], acc[m][n], 0, 0, 0);
      }
    }

    u16x8 pf; float f = 1.f;
    if (have) softmax(ar, pf, f);      // A-load latency hidden under MFMA above

    __syncthreads();                   // all MFMA(i) done reading sP
    if (have) {
      *(u16x8*)(sP + r0 * 64 + hhP) = pf;
      if (cc == 0) sF[r0] = f;
      int fl = __any(f < 1.f) ? 1 : 0;
      if (lane == 0) sFlag[wave] = fl;
    }
  }

  // ---- epilogue: normalize and store
  if (cc == 0) sL[r0] = 1.0f / lrun;
  __syncthreads();
#pragma unroll
  for (int m = 0; m < 4; ++m) {
    f32x4 li = *(const f32x4*)&sL[wr * 64 + m * 16 + lhi * 4];
#pragma unroll
    for (int r = 0; r < 4; ++r) {
      int grow = rt * 128 + wr * 64 + m * 16 + lhi * 4 + r;
#pragma unroll
      for (int n = 0; n < 4; ++n) {
        int col = wn * 64 + n * 16 + l15;
        out[((size_t)bg * LQ + grow) * EMB + col] = acc[m][n][r] * li[r];
      }
    }
  }
}

// ---------------- host ----------------------------------------------------
extern "C" void kernel_launch(void* const* d_in, const int* in_sizes, int n_in,
                              void* d_out, int out_size, void* d_ws, size_t ws_size,
                              hipStream_t stream) {
  const float* x  = (const float*)d_in[0];
  const float* Wq = (const float*)d_in[1];
  const float* bq = (const float*)d_in[2];
  const float* Wk = (const float*)d_in[3];
  const float* bk = (const float*)d_in[4];
  const float* Wv = (const float*)d_in[5];
  const float* bv = (const float*)d_in[6];

  char* ws = (char*)d_ws;
  size_t off = 0;
  u16* xb  = (u16*)(ws + off); off += (size_t)MROWS * EMB * 2;
  u16* wqb = (u16*)(ws + off); off += (size_t)EMB * EMB * 2;
  u16* wkb = (u16*)(ws + off); off += (size_t)EMB * EMB * 2;
  u16* wvb = (u16*)(ws + off); off += (size_t)EMB * EMB * 2;
  float* bias = (float*)(ws + off); off += 3 * EMB * 4;
  off = (off + 255) & ~(size_t)255;
  u16* Qb  = (u16*)(ws + off); off += (size_t)MROWS * EMB * 2;
  u16* Kb  = (u16*)(ws + off); off += (size_t)MROWS * EMB * 2;
  u16* Vtb = (u16*)(ws + off); off += (size_t)MROWS * EMB * 2;
  size_t fixed = off;
  size_t s_full = (size_t)NB * LQ * LQ * 2;
  int bcap = (ws_size >= fixed + s_full) ? NB : 1;
  u16* Sb = (u16*)(ws + fixed);

  prep_w<<<(EMB * EMB + 255) / 256, 256, 0, stream>>>(Wq, bq, Wk, bk, Wv, bv,
                                                      wqb, wkb, wvb, bias);
  prep_x<<<(MROWS * EMB / 8) / 256, 256, 0, stream>>>(x, xb);

  k_qkv<<<1536, 256, 0, stream>>>(xb, wqb, wkb, wvb, bias, Qb, Kb, Vtb);

  for (int bs = 0; bs < NB; bs += bcap) {
    int bc = (bs + bcap <= NB) ? bcap : (NB - bs);
    k_qk<<<528 * bc, 256, 0, stream>>>(Qb, Kb, Sb, bs);
    k_pv3<<<32 * bc, 1024, 0, stream>>>(Sb, Vtb, (float*)d_out, bs, bc);
  }
}

// Round 8
// 236.737 us; speedup vs baseline: 1.8527x; 1.1694x over previous
//
#include <hip/hip_runtime.h>

typedef unsigned short u16;
typedef unsigned int u32;
typedef short bf16x8 __attribute__((ext_vector_type(8)));
typedef float f32x4 __attribute__((ext_vector_type(4)));
typedef u16 u16x8 __attribute__((ext_vector_type(8)));
typedef u16 u16x4 __attribute__((ext_vector_type(4)));

typedef const __attribute__((address_space(1))) u32* gas_ptr;
typedef __attribute__((address_space(3))) u32* las_ptr;

#define LQ   4096
#define EMB  512
#define NB   4
#define MROWS (NB * LQ)            // 16384
#define QSCALE 0.04419417382415922f // 1/sqrt(512)

__device__ __forceinline__ u16 f2bf(float f) {
  unsigned u = __builtin_bit_cast(unsigned, f);
  u += 0x7fffu + ((u >> 16) & 1u);
  return (u16)(u >> 16);
}
__device__ __forceinline__ float bf2f(u16 h) {
  unsigned u = ((unsigned)h) << 16;
  return __builtin_bit_cast(float, u);
}

// ---------------- prep ----------------------------------------------------
__global__ void prep_w(const float* __restrict__ Wq, const float* __restrict__ bq,
                       const float* __restrict__ Wk, const float* __restrict__ bk,
                       const float* __restrict__ Wv, const float* __restrict__ bv,
                       u16* __restrict__ wqb, u16* __restrict__ wkb, u16* __restrict__ wvb,
                       float* __restrict__ bias) {
  int i = blockIdx.x * 256 + threadIdx.x;
  if (i < EMB * EMB) {
    wqb[i] = f2bf(Wq[i] * QSCALE);
    wkb[i] = f2bf(Wk[i]);
    wvb[i] = f2bf(Wv[i]);
  }
  if (i < EMB) {
    bias[i]           = bq[i] * QSCALE;
    bias[EMB + i]     = bk[i];
    bias[2 * EMB + i] = bv[i];
  }
}

__global__ void prep_x(const float* __restrict__ x, u16* __restrict__ xb) {
  int i = blockIdx.x * 256 + threadIdx.x;
  const float4* p = (const float4*)(x + (size_t)i * 8);
  float4 a = p[0], b = p[1];
  u16x8 o;
  o[0] = f2bf(a.x); o[1] = f2bf(a.y); o[2] = f2bf(a.z); o[3] = f2bf(a.w);
  o[4] = f2bf(b.x); o[5] = f2bf(b.y); o[6] = f2bf(b.z); o[7] = f2bf(b.w);
  *(u16x8*)(xb + (size_t)i * 8) = o;
}

// ---- stage one 128x64 bf16 tile (16KB) with 256 threads, gload_lds w=16 ---
__device__ __forceinline__ void stage128_256t(const u16* g, int ld, u16* lds, int tid) {
  int wave = tid >> 6;
#pragma unroll
  for (int p = 0; p < 4; ++p) {
    int c = tid + p * 256;           // chunk 0..1023
    int row = c >> 3, hh = c & 7;
    int h = hh ^ (row & 7);
    const u16* src = g + (size_t)row * ld + h * 8;
    u16* dst = lds + wave * 512 + p * 2048;
    __builtin_amdgcn_global_load_lds((gas_ptr)(const void*)src, (las_ptr)(void*)dst, 16, 0, 0);
  }
}

// ---- 128x128 GEMM core, dbuf + prefetch ----------------------------------
__device__ __forceinline__ void gemm_core_db(
    const u16* __restrict__ A, int lda,
    const u16* __restrict__ B, int ldb,
    int kIters, u16* lds,
    f32x4 acc[4][4], int tid, int lane, int wr, int wc)
{
  stage128_256t(A, lda, lds, tid);
  stage128_256t(B, ldb, lds + 8192, tid);
  for (int kb = 0; kb < kIters; ++kb) {
    u16* ldsA = lds + (kb & 1) * 16384;
    u16* ldsB = ldsA + 8192;
    __syncthreads();
    if (kb + 1 < kIters) {
      u16* nA = lds + ((kb + 1) & 1) * 16384;
      stage128_256t(A + (kb + 1) * 64, lda, nA, tid);
      stage128_256t(B + (kb + 1) * 64, ldb, nA + 8192, tid);
    }
#pragma unroll
    for (int s = 0; s < 2; ++s) {
      bf16x8 af[4], bfr[4];
#pragma unroll
      for (int m = 0; m < 4; ++m) {
        int row = wr * 64 + m * 16 + (lane & 15);
        int hh = (s * 4 + (lane >> 4)) ^ (row & 7);
        af[m] = *(const bf16x8*)(ldsA + row * 64 + hh * 8);
      }
#pragma unroll
      for (int n = 0; n < 4; ++n) {
        int row = wc * 64 + n * 16 + (lane & 15);
        int hh = (s * 4 + (lane >> 4)) ^ (row & 7);
        bfr[n] = *(const bf16x8*)(ldsB + row * 64 + hh * 8);
      }
#pragma unroll
      for (int m = 0; m < 4; ++m)
#pragma unroll
        for (int n = 0; n < 4; ++n)
          acc[m][n] = __builtin_amdgcn_mfma_f32_16x16x32_bf16(af[m], bfr[n], acc[m][n], 0, 0, 0);
    }
  }
}

// ---------------- K1: fused QKV projection GEMM --------------------------
__global__ __launch_bounds__(256, 2) void k_qkv(
    const u16* __restrict__ xb,
    const u16* __restrict__ w0, const u16* __restrict__ w1, const u16* __restrict__ w2,
    const float* __restrict__ bias,
    u16* __restrict__ o0, u16* __restrict__ o1, u16* __restrict__ o2)
{
  __shared__ __align__(16) u16 lds[32768];
  int bi = blockIdx.x;
  int which = bi >> 9;
  int t = bi & 511;
  int rt = t >> 2, ct = t & 3;
  const u16* W = (which == 0) ? w0 : (which == 1) ? w1 : w2;
  const float* bs = bias + which * EMB;
  int tid = threadIdx.x, lane = tid & 63, wave = tid >> 6;
  int wr = wave >> 1, wc = wave & 1;
  f32x4 acc[4][4];
#pragma unroll
  for (int m = 0; m < 4; ++m)
#pragma unroll
    for (int n = 0; n < 4; ++n) acc[m][n] = (f32x4)0.0f;

  gemm_core_db(xb + (size_t)rt * 128 * EMB, EMB,
               W + (size_t)ct * 128 * EMB, EMB, EMB / 64,
               lds, acc, tid, lane, wr, wc);

#pragma unroll
  for (int m = 0; m < 4; ++m)
#pragma unroll
    for (int n = 0; n < 4; ++n) {
      int row0 = rt * 128 + wr * 64 + m * 16 + ((lane >> 4) << 2);
      int col  = ct * 128 + wc * 64 + n * 16 + (lane & 15);
      float bv = bs[col];
      if (which < 2) {
        u16* out = (which == 0) ? o0 : o1;
#pragma unroll
        for (int r = 0; r < 4; ++r)
          out[(size_t)(row0 + r) * EMB + col] = f2bf(acc[m][n][r] + bv);
      } else {
        int b = row0 >> 12, l0 = row0 & (LQ - 1);
        u16x4 pk;
#pragma unroll
        for (int r = 0; r < 4; ++r) pk[r] = f2bf(acc[m][n][r] + bv);
        *(u16x4*)(o2 + ((size_t)(b * EMB + col)) * LQ + l0) = pk;
      }
    }
}

// ---------------- K2: S = Q K^T on causal (lower-tri) tiles --------------
__global__ __launch_bounds__(256, 2) void k_qk(
    const u16* __restrict__ Q, const u16* __restrict__ K,
    u16* __restrict__ S, int bstart)
{
  __shared__ __align__(16) u16 lds[32768];
  int t = blockIdx.x;
  int b_local = t / 528;
  int i = t - b_local * 528;
  int qi = (int)((sqrtf(8.f * (float)i + 1.f) - 1.f) * 0.5f);
  while ((qi + 1) * (qi + 2) / 2 <= i) ++qi;
  while (qi * (qi + 1) / 2 > i) --qi;
  int ki = i - qi * (qi + 1) / 2;
  int bg = bstart + b_local;

  int tid = threadIdx.x, lane = tid & 63, wave = tid >> 6;
  int wr = wave >> 1, wc = wave & 1;
  f32x4 acc[4][4];
#pragma unroll
  for (int m = 0; m < 4; ++m)
#pragma unroll
    for (int n = 0; n < 4; ++n) acc[m][n] = (f32x4)0.0f;

  gemm_core_db(Q + ((size_t)bg * LQ + qi * 128) * EMB, EMB,
               K + ((size_t)bg * LQ + ki * 128) * EMB, EMB, EMB / 64,
               lds, acc, tid, lane, wr, wc);

  u16* Sb = S + (size_t)b_local * LQ * LQ;
#pragma unroll
  for (int m = 0; m < 4; ++m)
#pragma unroll
    for (int n = 0; n < 4; ++n) {
      int row0 = qi * 128 + wr * 64 + m * 16 + ((lane >> 4) << 2);
      int col  = ki * 128 + wc * 64 + n * 16 + (lane & 15);
#pragma unroll
      for (int r = 0; r < 4; ++r) {
        int row = row0 + r;
        float v = (col > row) ? -1e9f : acc[m][n][r];
        Sb[(size_t)row * LQ + col] = f2bf(v);
      }
    }
}

// ---------------- K3: fused online-softmax + PV, M=128 / N=256 -----------
// 1024 thr / 16 waves (2M x 8N over 256 cols): acc[4][2] = 32 VGPR/thread;
// __launch_bounds__(1024,4) pins 1 block/CU -> 128-VGPR cap, no spill.
// ct=2 column split (V traffic NOT duplicated; S reads 2x, L3-cheap).
// Softmax once per S element (thread owns 1 row x 8 keys, 8-lane shfl).
// Pipeline: bar -> stageV(i+1) -> issueA(i+1) -> [rescale] -> MFMA(i)
//        -> softmax(i+1) -> bar -> publish P/sF/flag.
// LDS: V dbuf 64KB + P 16KB + stats ~81KB. Grid 32rt x 2ct x bc = 1/CU.
__global__ __launch_bounds__(1024, 4) void k_pv3(
    const u16* __restrict__ S, const u16* __restrict__ Vt,
    float* __restrict__ out, int bstart, int bcount)
{
  __shared__ __align__(16) u16 sV[32768];    // 2 bufs x [256 cols][64 keys]
  __shared__ __align__(16) u16 sP[8192];     // [128][64] swizzled
  __shared__ float sF[128];
  __shared__ float sL[128];
  __shared__ int   sFlag[16];

  int bi = blockIdx.x;
  int per = 2 * bcount;
  int rt = bi / per;
  int rem = bi - rt * per;
  int ct = rem / bcount;
  int b_local = rem - ct * bcount;
  int bg = bstart + b_local;
  int units = 2 * (rt + 1);

  const u16* Sbase = S + ((size_t)b_local * LQ + rt * 128) * LQ;
  const u16* Vb = Vt + ((size_t)bg * EMB + ct * 256) * LQ;

  int tid = threadIdx.x, lane = tid & 63, wave = tid >> 6;
  int l15 = lane & 15, lhi = lane >> 4;
  int wr = wave >> 3, wn = wave & 7;   // 2M x 8N (wave: 64 rows x 32 cols)
  int r0 = tid >> 3;                   // softmax row 0..127
  int cc = tid & 7;                    // 8-key chunk

  f32x4 acc[4][2];
#pragma unroll
  for (int m = 0; m < 4; ++m)
#pragma unroll
    for (int n = 0; n < 2; ++n) acc[m][n] = (f32x4)0.0f;
  float mrun = -3.0e38f, lrun = 0.f;

  auto stageV = [&](int i, u16* buf) {
    const u16* gb = Vb + i * 64;
#pragma unroll
    for (int p = 0; p < 2; ++p) {
      int c = tid + p * 1024;          // chunk 0..2047
      int col = c >> 3, h = (c & 7) ^ (col & 7);
      __builtin_amdgcn_global_load_lds(
          (gas_ptr)(const void*)(gb + (size_t)col * LQ + h * 8),
          (las_ptr)(void*)(buf + wave * 512 + p * 8192), 16, 0, 0);
    }
  };

  auto softmax = [&](u16x8 ar, u16x8& pf, float& fo) {
    float sv[8];
#pragma unroll
    for (int j = 0; j < 8; ++j) sv[j] = bf2f(ar[j]);
    float mx = fmaxf(fmaxf(fmaxf(sv[0], sv[1]), fmaxf(sv[2], sv[3])),
                     fmaxf(fmaxf(sv[4], sv[5]), fmaxf(sv[6], sv[7])));
#pragma unroll
    for (int off = 1; off <= 4; off <<= 1) mx = fmaxf(mx, __shfl_xor(mx, off));
    float mn = (mx > mrun + 8.f) ? mx : mrun;   // defer-max THR=8
    float f = __expf(mrun - mn);                // ==1 when max kept
    mrun = mn;
    float t = 0.f;
#pragma unroll
    for (int j = 0; j < 8; ++j) {
      float e = __expf(sv[j] - mrun);
      t += e;
      pf[j] = f2bf(e);
    }
#pragma unroll
    for (int off = 1; off <= 4; off <<= 1) t += __shfl_xor(t, off);
    lrun = lrun * f + t;
    fo = f;
  };

  int hhP = (cc ^ (r0 & 7)) * 8;       // swizzled u16 offset for this thread's P

  // ---- prologue: V(0), softmax(0), publish P(0)/sF/flag
  stageV(0, sV);
  {
    u16x8 ar = *(const u16x8*)(Sbase + (size_t)r0 * LQ + cc * 8);
    u16x8 pf; float f;
    softmax(ar, pf, f);
    *(u16x8*)(sP + r0 * 64 + hhP) = pf;
    if (cc == 0) sF[r0] = f;
    int fl = __any(f < 1.f) ? 1 : 0;
    if (lane == 0) sFlag[wave] = fl;
  }

  for (int i = 0; i < units; ++i) {
    u16* vb = sV + (i & 1) * 16384;
    __syncthreads();                   // V(i) staged, P(i)/sF/flag visible
    bool have = (i + 1 < units);
    if (have) stageV(i + 1, sV + ((i + 1) & 1) * 16384);
    u16x8 ar;
    if (have) ar = *(const u16x8*)(Sbase + (i + 1) * 64 + (size_t)r0 * LQ + cc * 8);

    // rescale acc by per-row factor when any row updated its max
    int4 fA = *(const int4*)&sFlag[0];
    int4 fB = *(const int4*)&sFlag[4];
    int4 fC = *(const int4*)&sFlag[8];
    int4 fD = *(const int4*)&sFlag[12];
    if ((fA.x | fA.y | fA.z | fA.w) | (fB.x | fB.y | fB.z | fB.w) |
        (fC.x | fC.y | fC.z | fC.w) | (fD.x | fD.y | fD.z | fD.w)) {
#pragma unroll
      for (int m = 0; m < 4; ++m) {
        f32x4 sf = *(const f32x4*)&sF[wr * 64 + m * 16 + lhi * 4];
#pragma unroll
        for (int n = 0; n < 2; ++n)
#pragma unroll
          for (int r = 0; r < 4; ++r) acc[m][n][r] *= sf[r];
      }
    }

    // ---- MFMA(i): P (shared) x V (per-wave 32 cols)
#pragma unroll
    for (int s = 0; s < 2; ++s) {
      bf16x8 bv[2];
#pragma unroll
      for (int n = 0; n < 2; ++n) {
        int col = wn * 32 + n * 16 + l15;
        bv[n] = *(const bf16x8*)(vb + col * 64 + ((s * 4 + lhi) ^ (col & 7)) * 8);
      }
#pragma unroll
      for (int m = 0; m < 4; ++m) {
        int row = wr * 64 + m * 16 + l15;
        bf16x8 pa = *(const bf16x8*)(sP + row * 64 + ((s * 4 + lhi) ^ (row & 7)) * 8);
#pragma unroll
        for (int n = 0; n < 2; ++n)
          acc[m][n] = __builtin_amdgcn_mfma_f32_16x16x32_bf16(pa, bv[n], acc[m][n], 0, 0, 0);
      }
    }

    u16x8 pf; float f = 1.f;
    if (have) softmax(ar, pf, f);      // A-load latency hidden under MFMA above

    __syncthreads();                   // all MFMA(i) done reading sP
    if (have) {
      *(u16x8*)(sP + r0 * 64 + hhP) = pf;
      if (cc == 0) sF[r0] = f;
      int fl = __any(f < 1.f) ? 1 : 0;
      if (lane == 0) sFlag[wave] = fl;
    }
  }

  // ---- epilogue: normalize and store
  if (cc == 0) sL[r0] = 1.0f / lrun;
  __syncthreads();
#pragma unroll
  for (int m = 0; m < 4; ++m) {
    f32x4 li = *(const f32x4*)&sL[wr * 64 + m * 16 + lhi * 4];
#pragma unroll
    for (int r = 0; r < 4; ++r) {
      int grow = rt * 128 + wr * 64 + m * 16 + lhi * 4 + r;
#pragma unroll
      for (int n = 0; n < 2; ++n) {
        int col = ct * 256 + wn * 32 + n * 16 + l15;
        out[((size_t)bg * LQ + grow) * EMB + col] = acc[m][n][r] * li[r];
      }
    }
  }
}

// ---------------- host ----------------------------------------------------
extern "C" void kernel_launch(void* const* d_in, const int* in_sizes, int n_in,
                              void* d_out, int out_size, void* d_ws, size_t ws_size,
                              hipStream_t stream) {
  const float* x  = (const float*)d_in[0];
  const float* Wq = (const float*)d_in[1];
  const float* bq = (const float*)d_in[2];
  const float* Wk = (const float*)d_in[3];
  const float* bk = (const float*)d_in[4];
  const float* Wv = (const float*)d_in[5];
  const float* bv = (const float*)d_in[6];

  char* ws = (char*)d_ws;
  size_t off = 0;
  u16* xb  = (u16*)(ws + off); off += (size_t)MROWS * EMB * 2;
  u16* wqb = (u16*)(ws + off); off += (size_t)EMB * EMB * 2;
  u16* wkb = (u16*)(ws + off); off += (size_t)EMB * EMB * 2;
  u16* wvb = (u16*)(ws + off); off += (size_t)EMB * EMB * 2;
  float* bias = (float*)(ws + off); off += 3 * EMB * 4;
  off = (off + 255) & ~(size_t)255;
  u16* Qb  = (u16*)(ws + off); off += (size_t)MROWS * EMB * 2;
  u16* Kb  = (u16*)(ws + off); off += (size_t)MROWS * EMB * 2;
  u16* Vtb = (u16*)(ws + off); off += (size_t)MROWS * EMB * 2;
  size_t fixed = off;
  size_t s_full = (size_t)NB * LQ * LQ * 2;
  int bcap = (ws_size >= fixed + s_full) ? NB : 1;
  u16* Sb = (u16*)(ws + fixed);

  prep_w<<<(EMB * EMB + 255) / 256, 256, 0, stream>>>(Wq, bq, Wk, bk, Wv, bv,
                                                      wqb, wkb, wvb, bias);
  prep_x<<<(MROWS * EMB / 8) / 256, 256, 0, stream>>>(x, xb);

  k_qkv<<<1536, 256, 0, stream>>>(xb, wqb, wkb, wvb, bias, Qb, Kb, Vtb);

  for (int bs = 0; bs < NB; bs += bcap) {
    int bc = (bs + bcap <= NB) ? bcap : (NB - bs);
    k_qk<<<528 * bc, 256, 0, stream>>>(Qb, Kb, Sb, bs);
    k_pv3<<<64 * bc, 1024, 0, stream>>>(Sb, Vtb, (float*)d_out, bs, bc);
  }
}

// Round 10
// 228.884 us; speedup vs baseline: 1.9163x; 1.0343x over previous
//
#include <hip/hip_runtime.h>

typedef unsigned short u16;
typedef unsigned int u32;
typedef short bf16x8 __attribute__((ext_vector_type(8)));
typedef float f32x4 __attribute__((ext_vector_type(4)));
typedef u16 u16x8 __attribute__((ext_vector_type(8)));
typedef u16 u16x4 __attribute__((ext_vector_type(4)));

typedef const __attribute__((address_space(1))) u32* gas_ptr;
typedef __attribute__((address_space(3))) u32* las_ptr;

#define LQ   4096
#define EMB  512
#define NB   4
#define MROWS (NB * LQ)            // 16384
#define QSCALE 0.04419417382415922f // 1/sqrt(512)

__device__ __forceinline__ u16 f2bf(float f) {
  unsigned u = __builtin_bit_cast(unsigned, f);
  u += 0x7fffu + ((u >> 16) & 1u);
  return (u16)(u >> 16);
}
__device__ __forceinline__ float bf2f(u16 h) {
  unsigned u = ((unsigned)h) << 16;
  return __builtin_bit_cast(float, u);
}

// ---------------- prep ----------------------------------------------------
__global__ void prep_w(const float* __restrict__ Wq, const float* __restrict__ bq,
                       const float* __restrict__ Wk, const float* __restrict__ bk,
                       const float* __restrict__ Wv, const float* __restrict__ bv,
                       u16* __restrict__ wqb, u16* __restrict__ wkb, u16* __restrict__ wvb,
                       float* __restrict__ bias) {
  int i = blockIdx.x * 256 + threadIdx.x;
  if (i < EMB * EMB) {
    wqb[i] = f2bf(Wq[i] * QSCALE);
    wkb[i] = f2bf(Wk[i]);
    wvb[i] = f2bf(Wv[i]);
  }
  if (i < EMB) {
    bias[i]           = bq[i] * QSCALE;
    bias[EMB + i]     = bk[i];
    bias[2 * EMB + i] = bv[i];
  }
}

__global__ void prep_x(const float* __restrict__ x, u16* __restrict__ xb) {
  int i = blockIdx.x * 256 + threadIdx.x;
  const float4* p = (const float4*)(x + (size_t)i * 8);
  float4 a = p[0], b = p[1];
  u16x8 o;
  o[0] = f2bf(a.x); o[1] = f2bf(a.y); o[2] = f2bf(a.z); o[3] = f2bf(a.w);
  o[4] = f2bf(b.x); o[5] = f2bf(b.y); o[6] = f2bf(b.z); o[7] = f2bf(b.w);
  *(u16x8*)(xb + (size_t)i * 8) = o;
}

// ---- stage one 128x64 bf16 tile (16KB) with 256 threads, gload_lds w=16 ---
__device__ __forceinline__ void stage128_256t(const u16* g, int ld, u16* lds, int tid) {
  int wave = tid >> 6;
#pragma unroll
  for (int p = 0; p < 4; ++p) {
    int c = tid + p * 256;           // chunk 0..1023
    int row = c >> 3, hh = c & 7;
    int h = hh ^ (row & 7);
    const u16* src = g + (size_t)row * ld + h * 8;
    u16* dst = lds + wave * 512 + p * 2048;
    __builtin_amdgcn_global_load_lds((gas_ptr)(const void*)src, (las_ptr)(void*)dst, 16, 0, 0);
  }
}

// ---- 128x128 GEMM core, dbuf + prefetch ----------------------------------
__device__ __forceinline__ void gemm_core_db(
    const u16* __restrict__ A, int lda,
    const u16* __restrict__ B, int ldb,
    int kIters, u16* lds,
    f32x4 acc[4][4], int tid, int lane, int wr, int wc)
{
  stage128_256t(A, lda, lds, tid);
  stage128_256t(B, ldb, lds + 8192, tid);
  for (int kb = 0; kb < kIters; ++kb) {
    u16* ldsA = lds + (kb & 1) * 16384;
    u16* ldsB = ldsA + 8192;
    __syncthreads();
    if (kb + 1 < kIters) {
      u16* nA = lds + ((kb + 1) & 1) * 16384;
      stage128_256t(A + (kb + 1) * 64, lda, nA, tid);
      stage128_256t(B + (kb + 1) * 64, ldb, nA + 8192, tid);
    }
#pragma unroll
    for (int s = 0; s < 2; ++s) {
      bf16x8 af[4], bfr[4];
#pragma unroll
      for (int m = 0; m < 4; ++m) {
        int row = wr * 64 + m * 16 + (lane & 15);
        int hh = (s * 4 + (lane >> 4)) ^ (row & 7);
        af[m] = *(const bf16x8*)(ldsA + row * 64 + hh * 8);
      }
#pragma unroll
      for (int n = 0; n < 4; ++n) {
        int row = wc * 64 + n * 16 + (lane & 15);
        int hh = (s * 4 + (lane >> 4)) ^ (row & 7);
        bfr[n] = *(const bf16x8*)(ldsB + row * 64 + hh * 8);
      }
#pragma unroll
      for (int m = 0; m < 4; ++m)
#pragma unroll
        for (int n = 0; n < 4; ++n)
          acc[m][n] = __builtin_amdgcn_mfma_f32_16x16x32_bf16(af[m], bfr[n], acc[m][n], 0, 0, 0);
    }
  }
}

// ---------------- K1: fused QKV projection GEMM --------------------------
__global__ __launch_bounds__(256, 2) void k_qkv(
    const u16* __restrict__ xb,
    const u16* __restrict__ w0, const u16* __restrict__ w1, const u16* __restrict__ w2,
    const float* __restrict__ bias,
    u16* __restrict__ o0, u16* __restrict__ o1, u16* __restrict__ o2)
{
  __shared__ __align__(16) u16 lds[32768];
  int bi = blockIdx.x;
  int which = bi >> 9;
  int t = bi & 511;
  int rt = t >> 2, ct = t & 3;
  const u16* W = (which == 0) ? w0 : (which == 1) ? w1 : w2;
  const float* bs = bias + which * EMB;
  int tid = threadIdx.x, lane = tid & 63, wave = tid >> 6;
  int wr = wave >> 1, wc = wave & 1;
  f32x4 acc[4][4];
#pragma unroll
  for (int m = 0; m < 4; ++m)
#pragma unroll
    for (int n = 0; n < 4; ++n) acc[m][n] = (f32x4)0.0f;

  gemm_core_db(xb + (size_t)rt * 128 * EMB, EMB,
               W + (size_t)ct * 128 * EMB, EMB, EMB / 64,
               lds, acc, tid, lane, wr, wc);

#pragma unroll
  for (int m = 0; m < 4; ++m)
#pragma unroll
    for (int n = 0; n < 4; ++n) {
      int row0 = rt * 128 + wr * 64 + m * 16 + ((lane >> 4) << 2);
      int col  = ct * 128 + wc * 64 + n * 16 + (lane & 15);
      float bv = bs[col];
      if (which < 2) {
        u16* out = (which == 0) ? o0 : o1;
#pragma unroll
        for (int r = 0; r < 4; ++r)
          out[(size_t)(row0 + r) * EMB + col] = f2bf(acc[m][n][r] + bv);
      } else {
        int b = row0 >> 12, l0 = row0 & (LQ - 1);
        u16x4 pk;
#pragma unroll
        for (int r = 0; r < 4; ++r) pk[r] = f2bf(acc[m][n][r] + bv);
        *(u16x4*)(o2 + ((size_t)(b * EMB + col)) * LQ + l0) = pk;
      }
    }
}

// ---------------- K2: S = Q K^T on causal (lower-tri) tiles --------------
__global__ __launch_bounds__(256, 2) void k_qk(
    const u16* __restrict__ Q, const u16* __restrict__ K,
    u16* __restrict__ S, int bstart)
{
  __shared__ __align__(16) u16 lds[32768];
  int t = blockIdx.x;
  int b_local = t / 528;
  int i = t - b_local * 528;
  int qi = (int)((sqrtf(8.f * (float)i + 1.f) - 1.f) * 0.5f);
  while ((qi + 1) * (qi + 2) / 2 <= i) ++qi;
  while (qi * (qi + 1) / 2 > i) --qi;
  int ki = i - qi * (qi + 1) / 2;
  int bg = bstart + b_local;

  int tid = threadIdx.x, lane = tid & 63, wave = tid >> 6;
  int wr = wave >> 1, wc = wave & 1;
  f32x4 acc[4][4];
#pragma unroll
  for (int m = 0; m < 4; ++m)
#pragma unroll
    for (int n = 0; n < 4; ++n) acc[m][n] = (f32x4)0.0f;

  gemm_core_db(Q + ((size_t)bg * LQ + qi * 128) * EMB, EMB,
               K + ((size_t)bg * LQ + ki * 128) * EMB, EMB, EMB / 64,
               lds, acc, tid, lane, wr, wc);

  u16* Sb = S + (size_t)b_local * LQ * LQ;
#pragma unroll
  for (int m = 0; m < 4; ++m)
#pragma unroll
    for (int n = 0; n < 4; ++n) {
      int row0 = qi * 128 + wr * 64 + m * 16 + ((lane >> 4) << 2);
      int col  = ki * 128 + wc * 64 + n * 16 + (lane & 15);
#pragma unroll
      for (int r = 0; r < 4; ++r) {
        int row = row0 + r;
        float v = (col > row) ? -1e9f : acc[m][n][r];
        Sb[(size_t)row * LQ + col] = f2bf(v);
      }
    }
}

// ---------------- K3: fused online-softmax + PV, counted-vmcnt pipeline ---
// M=128 / N=256, 1024 thr / 16 waves (2M x 8N), acc[4][2]=32 VGPR.
// V triple-buffered (stage i+2 in flight ACROSS barriers), sP/sF/sFlag
// double-buffered -> ONE raw s_barrier per unit, vmcnt never drained to 0
// in steady state (T3/T4). Cross-wave V visibility: each wave drains its
// own stage(i+1) via counted vmcnt BEFORE the barrier (m201 pattern).
// R9 fix: sP buffer is 128x64 u16 = 8192 elems PER BUFFER -> sP[16384],
// stride 8192 (R8's 4096 stride overlapped buffers and overran into sF).
__global__ __launch_bounds__(1024, 4) void k_pv3(
    const u16* __restrict__ S, const u16* __restrict__ Vt,
    float* __restrict__ out, int bstart, int bcount)
{
  __shared__ __align__(16) u16 sV[49152];    // 3 bufs x [256 cols][64 keys]
  __shared__ __align__(16) u16 sP[16384];    // 2 bufs x [128][64] swizzled
  __shared__ float sF[256];                  // 2 bufs x 128
  __shared__ float sL[128];
  __shared__ int   sFlag[32];                // 2 bufs x 16

  int bi = blockIdx.x;
  int per = 2 * bcount;
  int rt = bi / per;
  int rem = bi - rt * per;
  int ct = rem / bcount;
  int b_local = rem - ct * bcount;
  int bg = bstart + b_local;
  int units = 2 * (rt + 1);                  // >= 2

  const u16* Sbase = S + ((size_t)b_local * LQ + rt * 128) * LQ;
  const u16* Vb = Vt + ((size_t)bg * EMB + ct * 256) * LQ;

  int tid = threadIdx.x, lane = tid & 63, wave = tid >> 6;
  int l15 = lane & 15, lhi = lane >> 4;
  int wr = wave >> 3, wn = wave & 7;   // 2M x 8N (wave: 64 rows x 32 cols)
  int r0 = tid >> 3;                   // softmax row 0..127
  int cc = tid & 7;                    // 8-key chunk

  f32x4 acc[4][2];
#pragma unroll
  for (int m = 0; m < 4; ++m)
#pragma unroll
    for (int n = 0; n < 2; ++n) acc[m][n] = (f32x4)0.0f;
  float mrun = -3.0e38f, lrun = 0.f;

  auto stageV = [&](int i, u16* buf) {   // 2 gload_lds per thread
    const u16* gb = Vb + i * 64;
#pragma unroll
    for (int p = 0; p < 2; ++p) {
      int c = tid + p * 1024;          // chunk 0..2047
      int col = c >> 3, h = (c & 7) ^ (col & 7);
      __builtin_amdgcn_global_load_lds(
          (gas_ptr)(const void*)(gb + (size_t)col * LQ + h * 8),
          (las_ptr)(void*)(buf + wave * 512 + p * 8192), 16, 0, 0);
    }
  };

  auto softmax = [&](u16x8 ar, u16x8& pf, float& fo) {
    float sv[8];
#pragma unroll
    for (int j = 0; j < 8; ++j) sv[j] = bf2f(ar[j]);
    float mx = fmaxf(fmaxf(fmaxf(sv[0], sv[1]), fmaxf(sv[2], sv[3])),
                     fmaxf(fmaxf(sv[4], sv[5]), fmaxf(sv[6], sv[7])));
#pragma unroll
    for (int off = 1; off <= 4; off <<= 1) mx = fmaxf(mx, __shfl_xor(mx, off));
    float mn = (mx > mrun + 8.f) ? mx : mrun;   // defer-max THR=8
    float f = __expf(mrun - mn);                // ==1 when max kept
    mrun = mn;
    float t = 0.f;
#pragma unroll
    for (int j = 0; j < 8; ++j) {
      float e = __expf(sv[j] - mrun);
      t += e;
      pf[j] = f2bf(e);
    }
#pragma unroll
    for (int off = 1; off <= 4; off <<= 1) t += __shfl_xor(t, off);
    lrun = lrun * f + t;
    fo = f;
  };

  int hhP = (cc ^ (r0 & 7)) * 8;       // swizzled u16 offset for this thread's P

  auto publish = [&](int buf, u16x8 pf, float f) {
    *(u16x8*)(sP + buf * 8192 + r0 * 64 + hhP) = pf;
    if (cc == 0) sF[buf * 128 + r0] = f;
    int fl = __any(f < 1.f) ? 1 : 0;
    if (lane == 0) sFlag[buf * 16 + wave] = fl;
  };

  // ---- prologue: stage(0), A(0), stage(1); drain st0+A0; softmax(0)
  stageV(0, sV);
  u16x8 ar = *(const u16x8*)(Sbase + (size_t)r0 * LQ + cc * 8);
  stageV(1, sV + 16384);
  asm volatile("s_waitcnt vmcnt(2)" ::: "memory");   // st(0)+A(0) done, st(1) in flight
  __builtin_amdgcn_sched_barrier(0);
  {
    u16x8 pf; float f;
    softmax(ar, pf, f);
    publish(0, pf, f);
  }
  asm volatile("s_waitcnt lgkmcnt(0)" ::: "memory");
  __builtin_amdgcn_s_barrier();

  int vc = 0;                          // i % 3
  for (int i = 0; i < units; ++i) {
    u16* vb = sV + vc * 16384;
    u16* pb = sP + (i & 1) * 8192;
    bool haveA = (i + 1 < units);
    bool haveS = (i + 2 < units);

    if (haveA) ar = *(const u16x8*)(Sbase + (i + 1) * 64 + (size_t)r0 * LQ + cc * 8);
    if (haveS) {
      int vs = vc + 2; if (vs >= 3) vs -= 3;
      stageV(i + 2, sV + vs * 16384);
    }
    __builtin_amdgcn_sched_barrier(0);  // pin issues above the compute

    // rescale acc when any row updated its max last unit
    int fb = (i & 1) * 16;
    int anyf = 0;
#pragma unroll
    for (int q = 0; q < 16; ++q) anyf |= sFlag[fb + q];
    if (anyf) {
#pragma unroll
      for (int m = 0; m < 4; ++m) {
        f32x4 sf = *(const f32x4*)&sF[(i & 1) * 128 + wr * 64 + m * 16 + lhi * 4];
#pragma unroll
        for (int n = 0; n < 2; ++n)
#pragma unroll
          for (int r = 0; r < 4; ++r) acc[m][n][r] *= sf[r];
      }
    }

    // ---- MFMA(i): P (shared, buf i&1) x V (buf i%3, per-wave 32 cols)
#pragma unroll
    for (int s = 0; s < 2; ++s) {
      bf16x8 bv[2];
#pragma unroll
      for (int n = 0; n < 2; ++n) {
        int col = wn * 32 + n * 16 + l15;
        bv[n] = *(const bf16x8*)(vb + col * 64 + ((s * 4 + lhi) ^ (col & 7)) * 8);
      }
#pragma unroll
      for (int m = 0; m < 4; ++m) {
        int row = wr * 64 + m * 16 + l15;
        bf16x8 pa = *(const bf16x8*)(pb + row * 64 + ((s * 4 + lhi) ^ (row & 7)) * 8);
#pragma unroll
        for (int n = 0; n < 2; ++n)
          acc[m][n] = __builtin_amdgcn_mfma_f32_16x16x32_bf16(pa, bv[n], acc[m][n], 0, 0, 0);
      }
    }

    if (haveA) {
      // drain own stage(i+1) + A(i+1); leave stage(i+2) in flight
      if (haveS) asm volatile("s_waitcnt vmcnt(2)" ::: "memory");
      else       asm volatile("s_waitcnt vmcnt(0)" ::: "memory");
      __builtin_amdgcn_sched_barrier(0);
      u16x8 pf; float f;
      softmax(ar, pf, f);
      publish((i + 1) & 1, pf, f);
    }
    asm volatile("s_waitcnt lgkmcnt(0)" ::: "memory");
    __builtin_amdgcn_sched_barrier(0);
    __builtin_amdgcn_s_barrier();

    vc = (vc + 1 == 3) ? 0 : vc + 1;
  }

  // ---- epilogue: normalize and store
  if (cc == 0) sL[r0] = 1.0f / lrun;
  __syncthreads();
#pragma unroll
  for (int m = 0; m < 4; ++m) {
    f32x4 li = *(const f32x4*)&sL[wr * 64 + m * 16 + lhi * 4];
#pragma unroll
    for (int r = 0; r < 4; ++r) {
      int grow = rt * 128 + wr * 64 + m * 16 + lhi * 4 + r;
#pragma unroll
      for (int n = 0; n < 2; ++n) {
        int col = ct * 256 + wn * 32 + n * 16 + l15;
        out[((size_t)bg * LQ + grow) * EMB + col] = acc[m][n][r] * li[r];
      }
    }
  }
}

// ---------------- host ----------------------------------------------------
extern "C" void kernel_launch(void* const* d_in, const int* in_sizes, int n_in,
                              void* d_out, int out_size, void* d_ws, size_t ws_size,
                              hipStream_t stream) {
  const float* x  = (const float*)d_in[0];
  const float* Wq = (const float*)d_in[1];
  const float* bq = (const float*)d_in[2];
  const float* Wk = (const float*)d_in[3];
  const float* bk = (const float*)d_in[4];
  const float* Wv = (const float*)d_in[5];
  const float* bv = (const float*)d_in[6];

  char* ws = (char*)d_ws;
  size_t off = 0;
  u16* xb  = (u16*)(ws + off); off += (size_t)MROWS * EMB * 2;
  u16* wqb = (u16*)(ws + off); off += (size_t)EMB * EMB * 2;
  u16* wkb = (u16*)(ws + off); off += (size_t)EMB * EMB * 2;
  u16* wvb = (u16*)(ws + off); off += (size_t)EMB * EMB * 2;
  float* bias = (float*)(ws + off); off += 3 * EMB * 4;
  off = (off + 255) & ~(size_t)255;
  u16* Qb  = (u16*)(ws + off); off += (size_t)MROWS * EMB * 2;
  u16* Kb  = (u16*)(ws + off); off += (size_t)MROWS * EMB * 2;
  u16* Vtb = (u16*)(ws + off); off += (size_t)MROWS * EMB * 2;
  size_t fixed = off;
  size_t s_full = (size_t)NB * LQ * LQ * 2;
  int bcap = (ws_size >= fixed + s_full) ? NB : 1;
  u16* Sb = (u16*)(ws + fixed);

  prep_w<<<(EMB * EMB + 255) / 256, 256, 0, stream>>>(Wq, bq, Wk, bk, Wv, bv,
                                                      wqb, wkb, wvb, bias);
  prep_x<<<(MROWS * EMB / 8) / 256, 256, 0, stream>>>(x, xb);

  k_qkv<<<1536, 256, 0, stream>>>(xb, wqb, wkb, wvb, bias, Qb, Kb, Vtb);

  for (int bs = 0; bs < NB; bs += bcap) {
    int bc = (bs + bcap <= NB) ? bcap : (NB - bs);
    k_qk<<<528 * bc, 256, 0, stream>>>(Qb, Kb, Sb, bs);
    k_pv3<<<64 * bc, 1024, 0, stream>>>(Sb, Vtb, (float*)d_out, bs, bc);
  }
}